// Round 4
// baseline (1128.772 us; speedup 1.0000x reference)
//
#include <hip/hip_runtime.h>

typedef float f32x4 __attribute__((ext_vector_type(4)));
typedef float f32x2 __attribute__((ext_vector_type(2)));
typedef short s16x8 __attribute__((ext_vector_type(8)));
typedef __bf16 bf16x8 __attribute__((ext_vector_type(8)));

__device__ __forceinline__ unsigned short f2bf(float f) {
    unsigned int u = __builtin_bit_cast(unsigned int, f);
    u += 0x7FFFu + ((u >> 16) & 1u);
    return (unsigned short)(u >> 16);
}

__device__ __forceinline__ f32x4 MFMA(s16x8 a, s16x8 b, f32x4 c) {
    return __builtin_amdgcn_mfma_f32_16x16x32_bf16(
        __builtin_bit_cast(bf16x8, a), __builtin_bit_cast(bf16x8, b), c, 0, 0, 0);
}

__device__ __forceinline__ float sigm(float v) {
    return __builtin_amdgcn_rcpf(1.f + __builtin_amdgcn_exp2f(-1.4426950408889634f * v));
}
__device__ __forceinline__ float tanh_(float v) {
    return 2.f * __builtin_amdgcn_rcpf(1.f + __builtin_amdgcn_exp2f(-2.8853900817779268f * v)) - 1.f;
}

// async global->LDS: per-lane global src (base + lane*16B), wave-uniform LDS base.
__device__ __forceinline__ void async_issue(const unsigned short* src, unsigned short* ldsDst,
                                            int lane) {
    __builtin_amdgcn_global_load_lds(
        (const __attribute__((address_space(1))) void*)(src + lane * 8),
        (__attribute__((address_space(3))) void*)ldsDst, 16, 0, 0);
}

#define VMCNT(n) asm volatile("s_waitcnt vmcnt(" #n ")" ::: "memory")
#define LGKM(n)  asm volatile("s_waitcnt lgkmcnt(" #n ")" ::: "memory")
#define SCHED0   __builtin_amdgcn_sched_barrier(0)

// ---------------- prologue kernels ----------------

__global__ void wc_kernel(const float* __restrict__ Wih1, const float* __restrict__ W_enc,
                          const float* __restrict__ b_enc, float* __restrict__ WC,
                          float* __restrict__ benc) {
    int i = blockIdx.x * 256 + threadIdx.x;
    if (i >= 1024 * 35) return;
    int j = i / 35;
    int f = i - j * 35;
    const float* wr = Wih1 + j * 256;
    float s = 0.f;
    if (f < 34) {
        for (int e = 0; e < 256; ++e) s += wr[e] * W_enc[e * 34 + f];
        WC[j * 34 + f] = s;
    } else {
        for (int e = 0; e < 256; ++e) s += wr[e] * b_enc[e];
        benc[j] = s;
    }
}

// Pack W (row-major [srcRows, srcK]) into per-wave-sequential bf16 B-frag streams:
// linear s16x8 index ((ntb*KK + kk)*G + g)*64 + lane holds
//   W[g*gStride + ntb*16 + (lane&15)][kk*32 + (lane>>4)*8 + j]  (0 outside bounds)
__global__ void pack_kernel(const float* __restrict__ src, unsigned short* __restrict__ dst,
                            int NTB, int KK, int G, int gStride, int srcRows, int srcK) {
    int idx = blockIdx.x * 256 + threadIdx.x;
    int total = NTB * KK * G * 64;
    if (idx >= total) return;
    int lane = idx & 63, q = idx >> 6;
    int g = q % G; q /= G;
    int kk = q % KK;
    int ntb = q / KK;
    int row = g * gStride + ntb * 16 + (lane & 15);
    int kbase = kk * 32 + ((lane >> 4) & 3) * 8;
    s16x8 v;
    #pragma unroll
    for (int j = 0; j < 8; ++j) {
        int k = kbase + j;
        float fv = (row < srcRows && k < srcK) ? src[row * srcK + k] : 0.f;
        v[j] = (short)f2bf(fv);
    }
    *(s16x8*)(dst + (long)idx * 8) = v;
}

__global__ void bias_kernel(const float* bih1, const float* bhh1, const float* benc,
                            const float* bih2, const float* bhh2, const float* b_dec,
                            float* bs1a, float* bs1b, float* bs2, float* bdec) {
    int j = blockIdx.x * 256 + threadIdx.x;
    if (j < 1024) {
        float s = bih1[j] + bhh1[j];
        bs1a[j] = s + benc[j];
        bs1b[j] = s;
        bs2[j] = bih2[j] + bhh2[j];
    }
    if (j < 48) bdec[j] = (j < 34) ? b_dec[j] : 0.f;
}

// ---------------- fused LSTM kernel ----------------
//
// Activations live in LDS in FRAGMENT-LINEAR layout: block (u, mt) holds the
// MFMA A-fragment for k-tile u, row-tile mt: lane l's 16B at
//   base + (u*4 + mt)*520 + l*8   (shorts; 520 = 512 + 8-short pad for writes)
// element semantics: Act[mt*16 + (l&15)][u*32 + (l>>4)*8 + j].
// Reads are lane-contiguous ds_read_b128 (conflict-free, no address math).
//
// Per k-tile steady schedule (all waits pre-satisfied in steady state):
//   lgkm(4)   B(u) reads retired -> slot half reusable
//   issue 4x global_load_lds for B(u+2)
//   vmcnt(4)  B(u+1) landed (issued one iteration earlier)
//   ds_read B(u+1) -> breg, ds_read A(u+1) -> areg   (used NEXT iter)
//   lgkm(8) + sched_barrier(0)   tile-u operands retired (8 newer lgkm ops allowed)
//   16x MFMA on tile u
template<int KKIN>
__device__ __forceinline__ void cell_step(
    const unsigned short* Ain,   // frag-linear base (v*2080 + mt*520 + lane*8)
    const unsigned short* Ahid,
    const unsigned short* __restrict__ pWin,
    const unsigned short* __restrict__ pWhid,
    const float* Lbias, float (&cst)[2][4][4], unsigned short* Hout,
    unsigned short* Bst, int wave, int lane, int ln15, int quad) {
    constexpr int T = KKIN + 8;  // 10 or 16 (even)
    unsigned int hp[2][8];
    const int wv2 = wave * 2;

    #pragma unroll
    for (int s = 0; s < 2; ++s) {
        const int ntb = wv2 + s;
        const unsigned short* wIn  = pWin  + ntb * (KKIN * 2048);
        const unsigned short* wHid = pWhid + ntb * (8 * 2048);
        f32x4 acc[4][4];
        #pragma unroll
        for (int g = 0; g < 4; ++g)
            #pragma unroll
            for (int mt = 0; mt < 4; ++mt) acc[g][mt] = f32x4{0.f, 0.f, 0.f, 0.f};
        s16x8 a0[4], a1[4], b0[4], b1[4];

        auto bsrc = [&](int v) -> const unsigned short* {
            return (v < KKIN) ? wIn + v * 2048 : wHid + (v - KKIN) * 2048;
        };
        auto asrc = [&](int v) -> const unsigned short* {
            return (v < KKIN) ? Ain + v * 2080 : Ahid + (v - KKIN) * 2080;
        };
        auto issue4 = [&](const unsigned short* src, int slotbase) {
            async_issue(src,        Bst + (slotbase + 0) * 512, lane);
            async_issue(src + 512,  Bst + (slotbase + 1) * 512, lane);
            async_issue(src + 1024, Bst + (slotbase + 2) * 512, lane);
            async_issue(src + 1536, Bst + (slotbase + 3) * 512, lane);
        };
        auto readB = [&](int slotbase, s16x8 (&b)[4]) {
            #pragma unroll
            for (int g = 0; g < 4; ++g)
                b[g] = *(const s16x8*)(Bst + (slotbase + g) * 512 + lane * 8);
        };
        auto readA = [&](const unsigned short* ab, s16x8 (&a)[4]) {
            #pragma unroll
            for (int mt = 0; mt < 4; ++mt)
                a[mt] = *(const s16x8*)(ab + mt * 520 + lane * 8);
        };
        auto mfma16 = [&](s16x8 (&b)[4], s16x8 (&a)[4]) {
            #pragma unroll
            for (int g = 0; g < 4; ++g)
                #pragma unroll
                for (int mt = 0; mt < 4; ++mt)
                    acc[g][mt] = MFMA(a[mt], b[g], acc[g][mt]);
        };

        // prologue: 2 k-tiles in flight, tile 0 operands in regs
        issue4(bsrc(0), 0);
        issue4(bsrc(1), 4);
        VMCNT(4);
        readB(0, b0);
        readA(asrc(0), a0);
        LGKM(0); SCHED0;

        #pragma unroll 1
        for (int i = 0; i < T - 2; i += 2) {
            // tile i (operands in b0/a0); prefetch i+1; issue B(i+2)
            LGKM(4);
            issue4(bsrc(i + 2), 0);
            VMCNT(4);
            readB(4, b1);
            readA(asrc(i + 1), a1);
            LGKM(8); SCHED0;
            mfma16(b0, a0);
            // tile i+1; prefetch i+2; issue B(i+3)
            LGKM(4);
            issue4(bsrc(i + 3), 4);
            VMCNT(4);
            readB(0, b0);
            readA(asrc(i + 2), a0);
            LGKM(8); SCHED0;
            mfma16(b1, a1);
        }
        // tail pair (T-2, T-1): no more issues
        LGKM(4);
        VMCNT(0);
        readB(4, b1);
        readA(asrc(T - 1), a1);
        LGKM(8); SCHED0;
        mfma16(b0, a0);
        LGKM(0); SCHED0;
        mfma16(b1, a1);

        const int colB = ntb * 16 + ln15;
        const float bi = Lbias[colB], bff = Lbias[256 + colB];
        const float bg = Lbias[512 + colB], bo = Lbias[768 + colB];
        #pragma unroll
        for (int mt = 0; mt < 4; ++mt) {
            #pragma unroll
            for (int r = 0; r < 4; ++r) {
                float iv = acc[0][mt][r] + bi;
                float fv = acc[1][mt][r] + bff;
                float gv = acc[2][mt][r] + bg;
                float ov = acc[3][mt][r] + bo;
                float cn = sigm(fv) * cst[s][mt][r] + sigm(iv) * tanh_(gv);
                cst[s][mt][r] = cn;
                float hv = sigm(ov) * tanh_(cn);
                unsigned int hb = (unsigned int)f2bf(hv);
                if ((r & 1) == 0) hp[s][mt * 2 + (r >> 1)] = hb;
                else              hp[s][mt * 2 + (r >> 1)] |= (hb << 16);
            }
        }
    }
    __syncthreads();  // all waves done reading h-buffers
    // scatter new h into frag-linear layout:
    // element (row=mt*16+quad*4+r, col=(2*wave+s)*16+ln15) ->
    //   block (u=wave, mt); laneA=(quad*4+r) | ((2s+(ln15>>3))<<4); j=ln15&7
    #pragma unroll
    for (int s = 0; s < 2; ++s)
        #pragma unroll
        for (int mt = 0; mt < 4; ++mt)
            #pragma unroll
            for (int r = 0; r < 4; ++r)
                Hout[(wave * 4 + mt) * 520 + (quad * 4 + r) * 8 +
                     (2 * s + (ln15 >> 3)) * 128 + (ln15 & 7)] =
                    (unsigned short)(hp[s][mt * 2 + (r >> 1)] >> ((r & 1) * 16));
    __syncthreads();  // new h visible
}

// LDS: h1f 33280 + h2f 33280 + scratch 12288 + Lb 12288 + Lbd 256 + Bring 65536 = 156928 B.
__global__ __launch_bounds__(512, 1) void lstm_fused(
    const float* __restrict__ x,
    const unsigned short* __restrict__ pWC,
    const unsigned short* __restrict__ pWih1,
    const unsigned short* __restrict__ pWhh1,
    const unsigned short* __restrict__ pWih2,
    const unsigned short* __restrict__ pWhh2,
    const unsigned short* __restrict__ pWdec,
    const float* __restrict__ gb1a, const float* __restrict__ gb1b,
    const float* __restrict__ gb2, const float* __restrict__ gbd,
    float* __restrict__ out) {
    extern __shared__ unsigned char smem[];
    unsigned short* h1f = (unsigned short*)smem;                  // 16640 shorts (8u x 4mt x 520)
    unsigned short* h2f = h1f + 16640;
    unsigned char* scratch = (unsigned char*)(h2f + 16640);       // 12288 B union:
    unsigned short* xfrag = (unsigned short*)scratch;             //   obs: 2u x 4mt x 520 = 8320 B
    float* dOut = (float*)scratch;                                //   dec: 64 x 48 f32 = 12288 B
    float* Lb1a = (float*)(scratch + 12288);
    float* Lb1b = Lb1a + 1024;
    float* Lb2  = Lb1b + 1024;
    float* Lbd  = Lb2 + 1024;                                     // 48 used (256 B)
    unsigned short* Bring = (unsigned short*)(scratch + 12288 + 12288 + 256);  // 65536 B

    const int tid = threadIdx.x;
    const int wave = tid >> 6;
    const int lane = tid & 63;
    const int ln15 = lane & 15;
    const int quad = lane >> 4;
    const int m0 = blockIdx.x * 64;
    unsigned short* Bst = Bring + wave * 4096;  // this wave's 8KB (8 slots x 1KB)

    for (int i = tid; i < 16640; i += 512) ((int*)h1f)[i] = 0;    // h1f+h2f (contiguous)
    for (int i = tid; i < 3072; i += 512) ((int*)scratch)[i] = 0;
    for (int i = tid; i < 1024; i += 512) { Lb1a[i] = gb1a[i]; Lb1b[i] = gb1b[i]; Lb2[i] = gb2[i]; }
    if (tid < 48) Lbd[tid] = gbd[tid];

    float c1[2][4][4], c2[2][4][4];
    #pragma unroll
    for (int s = 0; s < 2; ++s)
        #pragma unroll
        for (int mt = 0; mt < 4; ++mt)
            #pragma unroll
            for (int r = 0; r < 4; ++r) { c1[s][mt][r] = 0.f; c2[s][mt][r] = 0.f; }

    __syncthreads();

    #pragma unroll 1
    for (int t = 0; t < 19; ++t) {
        if (t < 10) {
            // stage x_t -> xfrag (bf16, fragment-linear; chunks for cols 34..63 stay zero)
            for (int i = tid; i < 1088; i += 512) {
                int r = i / 17, p = i - r * 17;
                int c = 2 * p;
                f32x2 v = __builtin_nontemporal_load((const f32x2*)(x + (m0 + r) * 340 + t * 34) + p);
                int u = c >> 5, mt = r >> 4;
                int laneA = (r & 15) | (((c >> 3) & 3) << 4);
                unsigned int packed = (unsigned int)f2bf(v.x) | ((unsigned int)f2bf(v.y) << 16);
                *(unsigned int*)(xfrag + (u * 4 + mt) * 520 + laneA * 8 + (c & 7)) = packed;
            }
            __syncthreads();
            cell_step<2>(xfrag, h1f, pWC, pWhh1, Lb1a, c1, h1f, Bst, wave, lane, ln15, quad);
        } else {
            cell_step<8>(h2f, h1f, pWih1, pWhh1, Lb1b, c1, h1f, Bst, wave, lane, ln15, quad);
        }
        cell_step<8>(h1f, h2f, pWih2, pWhh2, Lb2, c2, h2f, Bst, wave, lane, ln15, quad);

        if (t >= 9) {
            const int tout = t - 9;
            if (wave < 3) {  // decoder: dec = h2 @ W_dec^T + b_dec ; cumsum in dOut (LDS)
                f32x4 d[4];
                #pragma unroll
                for (int mt = 0; mt < 4; ++mt) d[mt] = f32x4{0.f, 0.f, 0.f, 0.f};
                #pragma unroll
                for (int kk = 0; kk < 8; ++kk) {
                    s16x8 b = *((const s16x8*)pWdec + (wave * 8 + kk) * 64 + lane);
                    #pragma unroll
                    for (int mt = 0; mt < 4; ++mt) {
                        s16x8 a = *(const s16x8*)(h2f + (kk * 4 + mt) * 520 + lane * 8);
                        d[mt] = MFMA(a, b, d[mt]);
                    }
                }
                const int col = wave * 16 + ln15;
                const bool valid = (col < 34);
                const float bd = Lbd[col];
                #pragma unroll
                for (int mt = 0; mt < 4; ++mt) {
                    #pragma unroll
                    for (int r = 0; r < 4; ++r) {
                        const int rloc = mt * 16 + quad * 4 + r;
                        float v = d[mt][r] + bd;
                        if (tout == 0) {
                            float xr = valid ? __builtin_nontemporal_load(x + (m0 + rloc) * 340 + 306 + col) : 0.f;
                            dOut[rloc * 48 + col] = v + xr;
                        } else {
                            dOut[rloc * 48 + col] += v;
                        }
                    }
                }
            }
            __syncthreads();
            // contiguous per-row non-temporal stores
            for (int i = tid; i < 1088; i += 512) {
                int r = i / 17, p = i - r * 17;
                f32x2 v = *(const f32x2*)(dOut + r * 48 + p * 2);
                __builtin_nontemporal_store(v, (f32x2*)(out + (m0 + r) * 340 + tout * 34) + p);
            }
            // no barrier needed: dOut is rewritten only after cell barriers of step t+1
        }
    }
}

// ---------------- launch ----------------

extern "C" void kernel_launch(void* const* d_in, const int* in_sizes, int n_in,
                              void* d_out, int out_size, void* d_ws, size_t ws_size,
                              hipStream_t stream) {
    const float* x     = (const float*)d_in[0];
    const float* W_enc = (const float*)d_in[1];
    const float* b_enc = (const float*)d_in[2];
    const float* Wih1  = (const float*)d_in[3];
    const float* Whh1  = (const float*)d_in[4];
    const float* bih1  = (const float*)d_in[5];
    const float* bhh1  = (const float*)d_in[6];
    const float* Wih2  = (const float*)d_in[7];
    const float* Whh2  = (const float*)d_in[8];
    const float* bih2  = (const float*)d_in[9];
    const float* bhh2  = (const float*)d_in[10];
    const float* W_dec = (const float*)d_in[11];
    const float* b_dec = (const float*)d_in[12];
    float* out = (float*)d_out;

    unsigned char* w = (unsigned char*)d_ws;
    float* WC   = (float*)(w + 0);         // 139264
    float* benc = (float*)(w + 139264);    // 4096
    float* bs1a = (float*)(w + 143360);
    float* bs1b = (float*)(w + 147456);
    float* bs2  = (float*)(w + 151552);
    float* bdec = (float*)(w + 155648);    // 256
    unsigned short* pWC   = (unsigned short*)(w + 155904);   // 131072
    unsigned short* pWih1 = (unsigned short*)(w + 286976);   // 524288 each
    unsigned short* pWhh1 = (unsigned short*)(w + 811264);
    unsigned short* pWih2 = (unsigned short*)(w + 1335552);
    unsigned short* pWhh2 = (unsigned short*)(w + 1859840);
    unsigned short* pWdec = (unsigned short*)(w + 2384128);  // 24576

    wc_kernel<<<140, 256, 0, stream>>>(Wih1, W_enc, b_enc, WC, benc);
    pack_kernel<<<32, 256, 0, stream>>>(WC, pWC, 16, 2, 4, 256, 1024, 34);
    pack_kernel<<<128, 256, 0, stream>>>(Wih1, pWih1, 16, 8, 4, 256, 1024, 256);
    pack_kernel<<<128, 256, 0, stream>>>(Whh1, pWhh1, 16, 8, 4, 256, 1024, 256);
    pack_kernel<<<128, 256, 0, stream>>>(Wih2, pWih2, 16, 8, 4, 256, 1024, 256);
    pack_kernel<<<128, 256, 0, stream>>>(Whh2, pWhh2, 16, 8, 4, 256, 1024, 256);
    pack_kernel<<<6, 256, 0, stream>>>(W_dec, pWdec, 3, 8, 1, 0, 34, 256);
    bias_kernel<<<4, 256, 0, stream>>>(bih1, bhh1, benc, bih2, bhh2, b_dec, bs1a, bs1b, bs2, bdec);

    hipFuncSetAttribute((const void*)lstm_fused, hipFuncAttributeMaxDynamicSharedMemorySize, 156928);
    lstm_fused<<<256, 512, 156928, stream>>>(x, pWC, pWih1, pWhh1, pWih2, pWhh2, pWdec,
                                             bs1a, bs1b, bs2, bdec, out);
}

// Round 5
// 909.566 us; speedup vs baseline: 1.2410x; 1.2410x over previous
//
#include <hip/hip_runtime.h>

typedef float f32x4 __attribute__((ext_vector_type(4)));
typedef float f32x2 __attribute__((ext_vector_type(2)));
typedef short s16x8 __attribute__((ext_vector_type(8)));
typedef __bf16 bf16x8 __attribute__((ext_vector_type(8)));

__device__ __forceinline__ unsigned short f2bf(float f) {
    unsigned int u = __builtin_bit_cast(unsigned int, f);
    u += 0x7FFFu + ((u >> 16) & 1u);
    return (unsigned short)(u >> 16);
}

__device__ __forceinline__ f32x4 MFMA(s16x8 a, s16x8 b, f32x4 c) {
    return __builtin_amdgcn_mfma_f32_16x16x32_bf16(
        __builtin_bit_cast(bf16x8, a), __builtin_bit_cast(bf16x8, b), c, 0, 0, 0);
}

__device__ __forceinline__ float sigm(float v) {
    return __builtin_amdgcn_rcpf(1.f + __builtin_amdgcn_exp2f(-1.4426950408889634f * v));
}
__device__ __forceinline__ float tanh_(float v) {
    return 2.f * __builtin_amdgcn_rcpf(1.f + __builtin_amdgcn_exp2f(-2.8853900817779268f * v)) - 1.f;
}

// async global->LDS: per-lane global src (base + lane*16B), wave-uniform LDS base.
__device__ __forceinline__ void async_issue(const unsigned short* src, unsigned short* ldsDst,
                                            int lane) {
    __builtin_amdgcn_global_load_lds(
        (const __attribute__((address_space(1))) void*)(src + lane * 8),
        (__attribute__((address_space(3))) void*)ldsDst, 16, 0, 0);
}

#define VMCNT(n) asm volatile("s_waitcnt vmcnt(" #n ")" ::: "memory")
#define LGKM(n)  asm volatile("s_waitcnt lgkmcnt(" #n ")" ::: "memory")
#define SCHED0   __builtin_amdgcn_sched_barrier(0)

// ---------------- prologue kernels ----------------

__global__ void wc_kernel(const float* __restrict__ Wih1, const float* __restrict__ W_enc,
                          const float* __restrict__ b_enc, float* __restrict__ WC,
                          float* __restrict__ benc) {
    int i = blockIdx.x * 256 + threadIdx.x;
    if (i >= 1024 * 35) return;
    int j = i / 35;
    int f = i - j * 35;
    const float* wr = Wih1 + j * 256;
    float s = 0.f;
    if (f < 34) {
        for (int e = 0; e < 256; ++e) s += wr[e] * W_enc[e * 34 + f];
        WC[j * 34 + f] = s;
    } else {
        for (int e = 0; e < 256; ++e) s += wr[e] * b_enc[e];
        benc[j] = s;
    }
}

// Pack W (row-major [srcRows, srcK]) into per-wave-sequential bf16 B-frag streams:
// linear s16x8 index ((ntb*KK + kk)*G + g)*64 + lane holds
//   W[g*gStride + ntb*16 + (lane&15)][kk*32 + (lane>>4)*8 + j]  (0 outside bounds)
__global__ void pack_kernel(const float* __restrict__ src, unsigned short* __restrict__ dst,
                            int NTB, int KK, int G, int gStride, int srcRows, int srcK) {
    int idx = blockIdx.x * 256 + threadIdx.x;
    int total = NTB * KK * G * 64;
    if (idx >= total) return;
    int lane = idx & 63, q = idx >> 6;
    int g = q % G; q /= G;
    int kk = q % KK;
    int ntb = q / KK;
    int row = g * gStride + ntb * 16 + (lane & 15);
    int kbase = kk * 32 + ((lane >> 4) & 3) * 8;
    s16x8 v;
    #pragma unroll
    for (int j = 0; j < 8; ++j) {
        int k = kbase + j;
        float fv = (row < srcRows && k < srcK) ? src[row * srcK + k] : 0.f;
        v[j] = (short)f2bf(fv);
    }
    *(s16x8*)(dst + (long)idx * 8) = v;
}

__global__ void bias_kernel(const float* bih1, const float* bhh1, const float* benc,
                            const float* bih2, const float* bhh2, const float* b_dec,
                            float* bs1a, float* bs1b, float* bs2, float* bdec) {
    int j = blockIdx.x * 256 + threadIdx.x;
    if (j < 1024) {
        float s = bih1[j] + bhh1[j];
        bs1a[j] = s + benc[j];
        bs1b[j] = s;
        bs2[j] = bih2[j] + bhh2[j];
    }
    if (j < 48) bdec[j] = (j < 34) ? b_dec[j] : 0.f;
}

// ---------------- fused LSTM kernel ----------------
//
// A layout (frag-linear, R4-proven conflict-free): block (u, mt) at
//   base + (u*4 + mt)*520 + lane*8  (shorts); element = Act[mt*16+(l&15)][u*32+(l>>4)*8+j].
//
// Register budget discipline (R0..R4 lesson: WRITE_SIZE tracks held operand regs):
//   aC[4] + aN[4] + b[4] = 96 arch VGPRs of operands, NOTHING more held.
//   acc (64) + c-state (64) fill the 128-AGPR half. Total 256 -> 2 waves/SIMD.
//
// Per-tile schedule (tiles v = s*T + u, flattened B-pipeline across s):
//   S1 ds_read aN <- A(v+1)          (4 ds ops; covered by whole tile)
//   S2 LGKM(4)                       queue = [b<-B(v) x4][aN x4] -> drains b-reads:
//                                    operands of THIS tile ready + slot-overwrite guard
//   S3 issue4 B(v+2) -> slots parity(v)   (async, zero regs)
//   S4 VMCNT(4)                      B(v+1) landed (4 newer = B(v+2))
//   g-units x4: MFMA x4 with b[g]; SCHED0; b[g] <- B(v+1) frag g   (after-use
//                overwrite: same register, no second buffer, ~1 tile to land)
// Pairs of tiles are unrolled so aC/aN alternate with compile-time indices.
template<int KKIN>
__device__ __forceinline__ void cell_step(
    const unsigned short* Ain,   // frag-linear (tile u at +u*2080)
    const unsigned short* Ahid,
    const unsigned short* __restrict__ pWin,
    const unsigned short* __restrict__ pWhid,
    const float* Lbias, float (&cst)[2][4][4], unsigned short* Hout,
    unsigned short* Bst, int wave, int lane, int ln15, int quad) {
    constexpr int T = KKIN + 8;  // 10 or 16 (even)
    unsigned int hp[2][8];
    const int wv2 = wave * 2;

    auto bsrc = [&](int v) -> const unsigned short* {  // v in [0, 2T)
        int ss = (v >= T) ? 1 : 0;
        int u = v - ss * T;
        int ntb = wv2 + ss;
        return (u < KKIN) ? pWin + (ntb * KKIN + u) * 2048
                          : pWhid + (ntb * 8 + (u - KKIN)) * 2048;
    };
    auto asrc = [&](int v) -> const unsigned short* {
        int u = (v >= T) ? v - T : v;
        return (u < KKIN) ? Ain + u * 2080 : Ahid + (u - KKIN) * 2080;
    };
    auto issue4 = [&](const unsigned short* src, int so) {
        async_issue(src,        Bst + so,        lane);
        async_issue(src + 512,  Bst + so + 512,  lane);
        async_issue(src + 1024, Bst + so + 1024, lane);
        async_issue(src + 1536, Bst + so + 1536, lane);
    };
    auto readA = [&](const unsigned short* ab, s16x8 (&a)[4]) {
        #pragma unroll
        for (int mt = 0; mt < 4; ++mt)
            a[mt] = *(const s16x8*)(ab + mt * 520 + lane * 8);
    };

    s16x8 aC[4], aN[4], b[4];
    f32x4 acc[4][4];

    // prologue: B(0)->slots0-3, B(1)->slots4-7; wait B(0); operands of tile 0
    issue4(bsrc(0), 0);
    issue4(bsrc(1), 2048);
    VMCNT(4);
    readA(asrc(0), aC);
    #pragma unroll
    for (int g = 0; g < 4; ++g)
        b[g] = *(const s16x8*)(Bst + g * 512 + lane * 8);

    #pragma unroll
    for (int s = 0; s < 2; ++s) {
        #pragma unroll
        for (int g = 0; g < 4; ++g)
            #pragma unroll
            for (int mt = 0; mt < 4; ++mt) acc[g][mt] = f32x4{0.f, 0.f, 0.f, 0.f};
        const int base = s * T;
        const int nrm = s ? (T - 2) : T;  // s=1: last 2 tiles peeled (drain)
        #pragma unroll 1
        for (int u = 0; u < nrm; u += 2) {
            const int v = base + u;  // always even (T even)
            // even tile v: use aC, fill aN; issue -> slots0; b <- slots4 (B(v+1))
            readA(asrc(v + 1), aN);
            LGKM(4);
            issue4(bsrc(v + 2), 0);
            VMCNT(4);
            #pragma unroll
            for (int g = 0; g < 4; ++g) {
                acc[g][0] = MFMA(aC[0], b[g], acc[g][0]);
                acc[g][1] = MFMA(aC[1], b[g], acc[g][1]);
                acc[g][2] = MFMA(aC[2], b[g], acc[g][2]);
                acc[g][3] = MFMA(aC[3], b[g], acc[g][3]);
                SCHED0;
                b[g] = *(const s16x8*)(Bst + 2048 + g * 512 + lane * 8);
            }
            // odd tile v+1: use aN, fill aC; issue -> slots4; b <- slots0 (B(v+2))
            readA(asrc(v + 2), aC);
            LGKM(4);
            issue4(bsrc(v + 3), 2048);
            VMCNT(4);
            #pragma unroll
            for (int g = 0; g < 4; ++g) {
                acc[g][0] = MFMA(aN[0], b[g], acc[g][0]);
                acc[g][1] = MFMA(aN[1], b[g], acc[g][1]);
                acc[g][2] = MFMA(aN[2], b[g], acc[g][2]);
                acc[g][3] = MFMA(aN[3], b[g], acc[g][3]);
                SCHED0;
                b[g] = *(const s16x8*)(Bst + g * 512 + lane * 8);
            }
        }
        if (s == 1) {
            // tail tile 2T-2 (even, aC): no issue; VMCNT(0) -> B(2T-1) landed
            readA(asrc(2 * T - 1), aN);
            LGKM(4);
            VMCNT(0);
            #pragma unroll
            for (int g = 0; g < 4; ++g) {
                acc[g][0] = MFMA(aC[0], b[g], acc[g][0]);
                acc[g][1] = MFMA(aC[1], b[g], acc[g][1]);
                acc[g][2] = MFMA(aC[2], b[g], acc[g][2]);
                acc[g][3] = MFMA(aC[3], b[g], acc[g][3]);
                SCHED0;
                b[g] = *(const s16x8*)(Bst + 2048 + g * 512 + lane * 8);
            }
            // tail tile 2T-1 (odd, aN): pure MFMA drain
            SCHED0;
            #pragma unroll
            for (int g = 0; g < 4; ++g) {
                acc[g][0] = MFMA(aN[0], b[g], acc[g][0]);
                acc[g][1] = MFMA(aN[1], b[g], acc[g][1]);
                acc[g][2] = MFMA(aN[2], b[g], acc[g][2]);
                acc[g][3] = MFMA(aN[3], b[g], acc[g][3]);
            }
        }

        const int colB = (wv2 + s) * 16 + ln15;
        const float bi = Lbias[colB], bff = Lbias[256 + colB];
        const float bg = Lbias[512 + colB], bo = Lbias[768 + colB];
        #pragma unroll
        for (int mt = 0; mt < 4; ++mt) {
            #pragma unroll
            for (int r = 0; r < 4; ++r) {
                float iv = acc[0][mt][r] + bi;
                float fv = acc[1][mt][r] + bff;
                float gv = acc[2][mt][r] + bg;
                float ov = acc[3][mt][r] + bo;
                float cn = sigm(fv) * cst[s][mt][r] + sigm(iv) * tanh_(gv);
                cst[s][mt][r] = cn;
                float hv = sigm(ov) * tanh_(cn);
                unsigned int hb = (unsigned int)f2bf(hv);
                if ((r & 1) == 0) hp[s][mt * 2 + (r >> 1)] = hb;
                else              hp[s][mt * 2 + (r >> 1)] |= (hb << 16);
            }
        }
    }
    __syncthreads();  // all waves done reading h-buffers
    // scatter new h into frag-linear layout:
    // element (row=mt*16+quad*4+r, col=(2*wave+s)*16+ln15) ->
    //   block (u=wave, mt); laneA=(quad*4+r) | ((2s+(ln15>>3))<<4); j=ln15&7
    #pragma unroll
    for (int s = 0; s < 2; ++s)
        #pragma unroll
        for (int mt = 0; mt < 4; ++mt)
            #pragma unroll
            for (int r = 0; r < 4; ++r)
                Hout[(wave * 4 + mt) * 520 + (quad * 4 + r) * 8 +
                     (2 * s + (ln15 >> 3)) * 128 + (ln15 & 7)] =
                    (unsigned short)(hp[s][mt * 2 + (r >> 1)] >> ((r & 1) * 16));
    __syncthreads();  // new h visible
}

// LDS: h1f 33280 + h2f 33280 + scratch 12288 + Lb 12288 + Lbd 256 + Bring 65536 = 156928 B.
__global__ __launch_bounds__(512, 2) void lstm_fused(
    const float* __restrict__ x,
    const unsigned short* __restrict__ pWC,
    const unsigned short* __restrict__ pWih1,
    const unsigned short* __restrict__ pWhh1,
    const unsigned short* __restrict__ pWih2,
    const unsigned short* __restrict__ pWhh2,
    const unsigned short* __restrict__ pWdec,
    const float* __restrict__ gb1a, const float* __restrict__ gb1b,
    const float* __restrict__ gb2, const float* __restrict__ gbd,
    float* __restrict__ out) {
    extern __shared__ unsigned char smem[];
    unsigned short* h1f = (unsigned short*)smem;                  // 16640 shorts (8u x 4mt x 520)
    unsigned short* h2f = h1f + 16640;
    unsigned char* scratch = (unsigned char*)(h2f + 16640);       // 12288 B union:
    unsigned short* xfrag = (unsigned short*)scratch;             //   obs: 2u x 4mt x 520 = 8320 B
    float* dOut = (float*)scratch;                                //   dec: 64 x 48 f32 = 12288 B
    float* Lb1a = (float*)(scratch + 12288);
    float* Lb1b = Lb1a + 1024;
    float* Lb2  = Lb1b + 1024;
    float* Lbd  = Lb2 + 1024;                                     // 48 used (256 B)
    unsigned short* Bring = (unsigned short*)(scratch + 12288 + 12288 + 256);  // 65536 B

    const int tid = threadIdx.x;
    const int wave = tid >> 6;
    const int lane = tid & 63;
    const int ln15 = lane & 15;
    const int quad = lane >> 4;
    const int m0 = blockIdx.x * 64;
    unsigned short* Bst = Bring + wave * 4096;  // this wave's 8KB (8 slots x 1KB)

    for (int i = tid; i < 16640; i += 512) ((int*)h1f)[i] = 0;    // h1f+h2f (contiguous)
    for (int i = tid; i < 3072; i += 512) ((int*)scratch)[i] = 0;
    for (int i = tid; i < 1024; i += 512) { Lb1a[i] = gb1a[i]; Lb1b[i] = gb1b[i]; Lb2[i] = gb2[i]; }
    if (tid < 48) Lbd[tid] = gbd[tid];

    float c1[2][4][4], c2[2][4][4];
    #pragma unroll
    for (int s = 0; s < 2; ++s)
        #pragma unroll
        for (int mt = 0; mt < 4; ++mt)
            #pragma unroll
            for (int r = 0; r < 4; ++r) { c1[s][mt][r] = 0.f; c2[s][mt][r] = 0.f; }

    __syncthreads();

    #pragma unroll 1
    for (int t = 0; t < 19; ++t) {
        if (t < 10) {
            // stage x_t -> xfrag (bf16, fragment-linear; chunks for cols 34..63 stay zero)
            for (int i = tid; i < 1088; i += 512) {
                int r = i / 17, p = i - r * 17;
                int c = 2 * p;
                f32x2 v = __builtin_nontemporal_load((const f32x2*)(x + (m0 + r) * 340 + t * 34) + p);
                int u = c >> 5, mt = r >> 4;
                int laneA = (r & 15) | (((c >> 3) & 3) << 4);
                unsigned int packed = (unsigned int)f2bf(v.x) | ((unsigned int)f2bf(v.y) << 16);
                *(unsigned int*)(xfrag + (u * 4 + mt) * 520 + laneA * 8 + (c & 7)) = packed;
            }
            __syncthreads();
            cell_step<2>(xfrag, h1f, pWC, pWhh1, Lb1a, c1, h1f, Bst, wave, lane, ln15, quad);
        } else {
            cell_step<8>(h2f, h1f, pWih1, pWhh1, Lb1b, c1, h1f, Bst, wave, lane, ln15, quad);
        }
        cell_step<8>(h1f, h2f, pWih2, pWhh2, Lb2, c2, h2f, Bst, wave, lane, ln15, quad);

        if (t >= 9) {
            const int tout = t - 9;
            if (wave < 3) {  // decoder: dec = h2 @ W_dec^T + b_dec ; cumsum in dOut (LDS)
                f32x4 d[4];
                #pragma unroll
                for (int mt = 0; mt < 4; ++mt) d[mt] = f32x4{0.f, 0.f, 0.f, 0.f};
                #pragma unroll
                for (int kk = 0; kk < 8; ++kk) {
                    s16x8 b = *((const s16x8*)pWdec + (wave * 8 + kk) * 64 + lane);
                    #pragma unroll
                    for (int mt = 0; mt < 4; ++mt) {
                        s16x8 a = *(const s16x8*)(h2f + (kk * 4 + mt) * 520 + lane * 8);
                        d[mt] = MFMA(a, b, d[mt]);
                    }
                }
                const int col = wave * 16 + ln15;
                const bool valid = (col < 34);
                const float bd = Lbd[col];
                #pragma unroll
                for (int mt = 0; mt < 4; ++mt) {
                    #pragma unroll
                    for (int r = 0; r < 4; ++r) {
                        const int rloc = mt * 16 + quad * 4 + r;
                        float v = d[mt][r] + bd;
                        if (tout == 0) {
                            float xr = valid ? __builtin_nontemporal_load(x + (m0 + rloc) * 340 + 306 + col) : 0.f;
                            dOut[rloc * 48 + col] = v + xr;
                        } else {
                            dOut[rloc * 48 + col] += v;
                        }
                    }
                }
            }
            __syncthreads();
            // contiguous per-row non-temporal stores
            for (int i = tid; i < 1088; i += 512) {
                int r = i / 17, p = i - r * 17;
                f32x2 v = *(const f32x2*)(dOut + r * 48 + p * 2);
                __builtin_nontemporal_store(v, (f32x2*)(out + (m0 + r) * 340 + tout * 34) + p);
            }
            // no barrier needed: dOut is rewritten only after cell barriers of step t+1
        }
    }
}

// ---------------- launch ----------------

extern "C" void kernel_launch(void* const* d_in, const int* in_sizes, int n_in,
                              void* d_out, int out_size, void* d_ws, size_t ws_size,
                              hipStream_t stream) {
    const float* x     = (const float*)d_in[0];
    const float* W_enc = (const float*)d_in[1];
    const float* b_enc = (const float*)d_in[2];
    const float* Wih1  = (const float*)d_in[3];
    const float* Whh1  = (const float*)d_in[4];
    const float* bih1  = (const float*)d_in[5];
    const float* bhh1  = (const float*)d_in[6];
    const float* Wih2  = (const float*)d_in[7];
    const float* Whh2  = (const float*)d_in[8];
    const float* bih2  = (const float*)d_in[9];
    const float* bhh2  = (const float*)d_in[10];
    const float* W_dec = (const float*)d_in[11];
    const float* b_dec = (const float*)d_in[12];
    float* out = (float*)d_out;

    unsigned char* w = (unsigned char*)d_ws;
    float* WC   = (float*)(w + 0);         // 139264
    float* benc = (float*)(w + 139264);    // 4096
    float* bs1a = (float*)(w + 143360);
    float* bs1b = (float*)(w + 147456);
    float* bs2  = (float*)(w + 151552);
    float* bdec = (float*)(w + 155648);    // 256
    unsigned short* pWC   = (unsigned short*)(w + 155904);   // 131072
    unsigned short* pWih1 = (unsigned short*)(w + 286976);   // 524288 each
    unsigned short* pWhh1 = (unsigned short*)(w + 811264);
    unsigned short* pWih2 = (unsigned short*)(w + 1335552);
    unsigned short* pWhh2 = (unsigned short*)(w + 1859840);
    unsigned short* pWdec = (unsigned short*)(w + 2384128);  // 24576

    wc_kernel<<<140, 256, 0, stream>>>(Wih1, W_enc, b_enc, WC, benc);
    pack_kernel<<<32, 256, 0, stream>>>(WC, pWC, 16, 2, 4, 256, 1024, 34);
    pack_kernel<<<128, 256, 0, stream>>>(Wih1, pWih1, 16, 8, 4, 256, 1024, 256);
    pack_kernel<<<128, 256, 0, stream>>>(Whh1, pWhh1, 16, 8, 4, 256, 1024, 256);
    pack_kernel<<<128, 256, 0, stream>>>(Wih2, pWih2, 16, 8, 4, 256, 1024, 256);
    pack_kernel<<<128, 256, 0, stream>>>(Whh2, pWhh2, 16, 8, 4, 256, 1024, 256);
    pack_kernel<<<6, 256, 0, stream>>>(W_dec, pWdec, 3, 8, 1, 0, 34, 256);
    bias_kernel<<<4, 256, 0, stream>>>(bih1, bhh1, benc, bih2, bhh2, b_dec, bs1a, bs1b, bs2, bdec);

    hipFuncSetAttribute((const void*)lstm_fused, hipFuncAttributeMaxDynamicSharedMemorySize, 156928);
    lstm_fused<<<256, 512, 156928, stream>>>(x, pWC, pWih1, pWhh1, pWih2, pWhh2, pWdec,
                                             bs1a, bs1b, bs2, bdec, out);
}